// Round 8
// baseline (704.876 us; speedup 1.0000x reference)
//
#include <hip/hip_runtime.h>

// ============================================================================
// XModel_66795331387584: complex phase-feature ridge loss on MI355X (gfx950)
//
// loss = mean_{a,z} sum_d | num_MN/den_MN - num_X/den_X |^2
// den path: split-bf16 (hi+lo), fp32 out (tail-dominated 1/|den|^2).
// gamma_X via 1-term Neumann: gx = (K12 - K@K12/reg)/reg (rel err 4e-6).
//
// R8: B-plane d-multipliers applied in-kernel (mult depends on k only ->
// scale the B fragment post-LDS-read with MTX[16][2048] row). Bt shrinks to
// 3 fixed full-z planes (gN h/l, gMN hi); k_prep runs ONCE; phases fused
// into k_gemm1 dispatch; converts+MTX in k_cvt. 7 dispatches (5 if ws>=241MB
// allows ZC=2048/NC=1).
// ============================================================================

typedef __bf16 bf16;
typedef __bf16 bf16x8 __attribute__((ext_vector_type(8)));
typedef float f32x4 __attribute__((ext_vector_type(4)));

#define AS1 __attribute__((address_space(1)))
#define AS3 __attribute__((address_space(3)))

__device__ __forceinline__ void async16(const void* g, void* l) {
  __builtin_amdgcn_global_load_lds((AS1 const unsigned int*)g,
                                   (AS3 unsigned int*)l, 16, 0, 0);
}

// ---------------- k_cvt: converts + MTX + out zero --------------------------
// bid [0,2048): K11->bf16 | [2048,3072): K12^T->hi/lo | 3072: MTX build
__global__ __launch_bounds__(256) void k_cvt(
    const float* __restrict__ K11, const float* __restrict__ K12,
    const float* __restrict__ Mm, const float* __restrict__ Xm,
    bf16* __restrict__ Kbf, bf16* __restrict__ K12T,
    bf16* __restrict__ K12TL, float* __restrict__ MTX,
    float* __restrict__ out) {
  __shared__ float t[64][65];
  const int bid = blockIdx.x, tid = threadIdx.x;
  if (bid < 2048) {
    if (bid == 0 && tid == 0) out[0] = 0.f;
    int e = (bid * 256 + tid) * 8;
    int j = e >> 11, k = e & 2047;
    bf16x8 v;
    if (j < 2000 && k < 2000) {
      const float4* s = (const float4*)(K11 + (size_t)j * 2000 + k);
      float4 f0 = s[0], f1 = s[1];
      v[0] = (bf16)f0.x; v[1] = (bf16)f0.y; v[2] = (bf16)f0.z; v[3] = (bf16)f0.w;
      v[4] = (bf16)f1.x; v[5] = (bf16)f1.y; v[6] = (bf16)f1.z; v[7] = (bf16)f1.w;
    } else {
      for (int i = 0; i < 8; ++i) v[i] = (bf16)0.f;
    }
    *(bf16x8*)(Kbf + e) = v;
  } else if (bid < 3072) {
    int b2 = bid - 2048;
    int j0 = (b2 & 31) * 64, z0 = (b2 >> 5) * 64;
    for (int e = tid; e < 4096; e += 256) {
      int r = e >> 6, c = e & 63;  // r=j row, c=z col
      t[r][c] = (j0 + r < 2000 && z0 + c < 2000)
                    ? K12[(size_t)(j0 + r) * 2000 + z0 + c] : 0.f;
    }
    __syncthreads();
#pragma unroll
    for (int it = 0; it < 2; ++it) {
      int idx = it * 256 + tid;
      int zr = idx >> 3, c8 = (idx & 7) * 8;
      bf16x8 vh, vl;
#pragma unroll
      for (int e = 0; e < 8; ++e) {
        float g = t[c8 + e][zr];
        bf16 h = (bf16)g;
        vh[e] = h;
        vl[e] = (bf16)(g - (float)h);
      }
      size_t ob = (size_t)(z0 + zr) * 2048 + j0 + c8;
      *(bf16x8*)(K12T + ob) = vh;
      *(bf16x8*)(K12TL + ob) = vl;
    }
  } else {
    // MTX[16][2048]: rows 0-7 = M_d[j], rows 8-15 = X_d[j]; zero-padded
    for (int j = tid; j < 2048; j += 256) {
      float mv[8], xv[8];
      if (j < 2000) {
        const float4* M4 = (const float4*)Mm;
        const float4* X4 = (const float4*)Xm;
        float4 ma = M4[j * 2], mb = M4[j * 2 + 1];
        float4 xa = X4[j * 2], xb = X4[j * 2 + 1];
        mv[0] = ma.x; mv[1] = ma.y; mv[2] = ma.z; mv[3] = ma.w;
        mv[4] = mb.x; mv[5] = mb.y; mv[6] = mb.z; mv[7] = mb.w;
        xv[0] = xa.x; xv[1] = xa.y; xv[2] = xa.z; xv[3] = xa.w;
        xv[4] = xb.x; xv[5] = xb.y; xv[6] = xb.z; xv[7] = xb.w;
      } else {
#pragma unroll
        for (int d = 0; d < 8; ++d) { mv[d] = 0.f; xv[d] = 0.f; }
      }
#pragma unroll
      for (int d = 0; d < 8; ++d) {
        MTX[d * 2048 + j] = mv[d];
        MTX[(8 + d) * 2048 + j] = xv[d];
      }
    }
  }
}

// --------------- k_gemm1 (+ fused phases tail blocks) -----------------------
// bid < 256: gamma_X GEMM tile; bid >= 256: phases for a = bid-256
__global__ __launch_bounds__(256, 2) void k_gemm1(
    const bf16* __restrict__ K12T, const bf16* __restrict__ K12TL,
    const bf16* __restrict__ Kbf, const float* __restrict__ ll,
    const float* __restrict__ al, const float* __restrict__ Nm,
    const float* __restrict__ Xm, bf16* __restrict__ gxHi,
    bf16* __restrict__ gxLo, bf16* __restrict__ AphH,
    bf16* __restrict__ AphL) {
  __shared__ __align__(16) char smem[34816];
  const int tid = threadIdx.x;
  const int bid = blockIdx.x;
  if (bid >= 256) {
    // ---- phases: a = bid-256, 8 j per thread, hi/lo bf16x8 stores
    const size_t PA = (size_t)1024 * 2048;
    int a = bid - 256;
    int j0 = tid * 8;
    float vc[4][8];
    if (a < 1000) {
      const float4* A4 = (const float4*)al;
      const float4* N4 = (const float4*)Nm;
      const float4* X4 = (const float4*)Xm;
      float4 a0 = A4[a * 2], a1 = A4[a * 2 + 1];
#pragma unroll
      for (int e = 0; e < 8; ++e) {
        int j = j0 + e;
        if (j < 2000) {
          float4 n0 = N4[j * 2], n1 = N4[j * 2 + 1];
          float4 x0 = X4[j * 2], x1 = X4[j * 2 + 1];
          float pn = a0.x * n0.x + a0.y * n0.y + a0.z * n0.z + a0.w * n0.w +
                     a1.x * n1.x + a1.y * n1.y + a1.z * n1.z + a1.w * n1.w;
          float px = a0.x * x0.x + a0.y * x0.y + a0.z * x0.z + a0.w * x0.w +
                     a1.x * x1.x + a1.y * x1.y + a1.z * x1.z + a1.w * x1.w;
          __sincosf(pn, &vc[1][e], &vc[0][e]);
          __sincosf(px, &vc[3][e], &vc[2][e]);
        } else {
          vc[0][e] = vc[1][e] = vc[2][e] = vc[3][e] = 0.f;
        }
      }
    } else {
#pragma unroll
      for (int p = 0; p < 4; ++p)
#pragma unroll
        for (int e = 0; e < 8; ++e) vc[p][e] = 0.f;
    }
    size_t o = (size_t)a * 2048 + j0;
#pragma unroll
    for (int p = 0; p < 4; ++p) {
      bf16x8 vh, vl;
#pragma unroll
      for (int e = 0; e < 8; ++e) {
        bf16 h = (bf16)vc[p][e];
        vh[e] = h;
        vl[e] = (bf16)(vc[p][e] - (float)h);
      }
      *(bf16x8*)(AphH + p * PA + o) = vh;
      *(bf16x8*)(AphL + p * PA + o) = vl;
    }
    return;
  }
  // ---- gamma_X tile
  bf16(*lds)[128][64] = (bf16(*)[128][64])smem;
  int bm = (bid >> 4) * 128;  // z-tile (global)
  int bn = (bid & 15) * 128;  // j-tile
  const int w = tid >> 6, ln = tid & 63;
  const int r8 = ln >> 3, c8 = (ln & 7) * 8;
  f32x4 acc[4][4];
#pragma unroll
  for (int i = 0; i < 4; i++)
#pragma unroll
    for (int j = 0; j < 4; j++) acc[i][j] = {0.f, 0.f, 0.f, 0.f};
  const int m0 = (w & 1) * 64, n0 = (w >> 1) * 64;
  const int fr = ln & 15, kq = (ln >> 4) * 8;
  for (int kt = 0; kt < 2048; kt += 64) {
#pragma unroll
    for (int q = 0; q < 4; ++q) {
      int row = (w * 4 + q) * 8 + r8;
      async16(K12T + (size_t)(bm + row) * 2048 + (kt + c8), &lds[0][row][c8]);
      async16(Kbf + (size_t)(bn + row) * 2048 + (kt + c8), &lds[1][row][c8]);
    }
    __syncthreads();
#pragma unroll
    for (int ks = 0; ks < 64; ks += 32) {
      bf16x8 a[4], b[4];
#pragma unroll
      for (int i = 0; i < 4; i++) {
        a[i] = *(const bf16x8*)&lds[0][m0 + i * 16 + fr][ks + kq];
        b[i] = *(const bf16x8*)&lds[1][n0 + i * 16 + fr][ks + kq];
      }
#pragma unroll
      for (int i = 0; i < 4; i++)
#pragma unroll
        for (int j = 0; j < 4; j++)
          acc[i][j] = __builtin_amdgcn_mfma_f32_16x16x32_bf16(
              a[i], b[j], acc[i][j], 0, 0, 0);
    }
    __syncthreads();
  }
  float inv = 1.f / (2000.f * __expf(ll[0]));
  float* ft = (float*)smem;  // [128][68]
  const int cr = (ln >> 4) * 4, cc = ln & 15;
  const int gtid = (tid & 7) * 8;
#pragma unroll
  for (int h = 0; h < 2; ++h) {
    if ((w >> 1) == h) {
#pragma unroll
      for (int i = 0; i < 4; i++)
#pragma unroll
        for (int j = 0; j < 4; j++)
#pragma unroll
          for (int r = 0; r < 4; r++)
            ft[(m0 + i * 16 + cr + r) * 68 + j * 16 + cc] = acc[i][j][r];
    }
    __syncthreads();
    int jbase = bn + h * 64 + gtid;
#pragma unroll
    for (int it = 0; it < 4; ++it) {
      int idx = it * 256 + tid;
      int m = idx >> 3;
      int zg = bm + m;
      size_t gb = (size_t)zg * 2048 + jbase;
      bf16x8 kh = *(const bf16x8*)(K12T + gb);
      bf16x8 klo = *(const bf16x8*)(K12TL + gb);
      bf16x8 vh, vl;
#pragma unroll
      for (int e = 0; e < 8; ++e) {
        float t1 = ft[m * 68 + gtid + e];
        float gx = ((float)kh[e] + (float)klo[e] - t1 * inv) * inv;
        bf16 hh = (bf16)gx;
        vh[e] = hh;
        vl[e] = (bf16)(gx - (float)hh);
      }
      *(bf16x8*)(gxHi + gb) = vh;
      *(bf16x8*)(gxLo + gb) = vl;
    }
    __syncthreads();
  }
}

// ------------- k_prep: ONCE, full-z 3-plane transpose -----------------------
// BtNh/BtNl = gN^T hi/lo; BtMN = gMN^T hi. All [2048][2048], zero-padded.
__global__ __launch_bounds__(256) void k_prep(
    const float* __restrict__ gN, const float* __restrict__ gMN,
    bf16* __restrict__ BtNh, bf16* __restrict__ BtNl,
    bf16* __restrict__ BtMN) {
  int j0 = blockIdx.x * 64, z0 = blockIdx.y * 64;
  int tid = threadIdx.x;
  __shared__ float t[64][65];

  for (int e = tid; e < 4096; e += 256) {
    int r = e >> 6, c = e & 63;
    t[r][c] = (j0 + r < 2000 && z0 + c < 2000)
                  ? gN[(size_t)(j0 + r) * 2000 + z0 + c] : 0.f;
  }
  __syncthreads();
#pragma unroll
  for (int it = 0; it < 2; ++it) {
    int idx = it * 256 + tid;
    int zr = idx >> 3, c8 = (idx & 7) * 8;
    bf16x8 vh, vl;
#pragma unroll
    for (int e = 0; e < 8; ++e) {
      float g = t[c8 + e][zr];
      bf16 h = (bf16)g;
      vh[e] = h;
      vl[e] = (bf16)(g - (float)h);
    }
    size_t ob = (size_t)(z0 + zr) * 2048 + j0 + c8;
    *(bf16x8*)(BtNh + ob) = vh;
    *(bf16x8*)(BtNl + ob) = vl;
  }
  __syncthreads();

  for (int e = tid; e < 4096; e += 256) {
    int r = e >> 6, c = e & 63;
    t[r][c] = (j0 + r < 2000 && z0 + c < 2000)
                  ? gMN[(size_t)(j0 + r) * 2000 + z0 + c] : 0.f;
  }
  __syncthreads();
#pragma unroll
  for (int it = 0; it < 2; ++it) {
    int idx = it * 256 + tid;
    int zr = idx >> 3, c8 = (idx & 7) * 8;
    bf16x8 v;
#pragma unroll
    for (int e = 0; e < 8; ++e) v[e] = (bf16)t[c8 + e][zr];
    *(bf16x8*)(BtMN + (size_t)(z0 + zr) * 2048 + j0 + c8) = v;
  }
}

// --------------------- unified num+den GEMM dispatch ------------------------
// zb<16: num plane (side = zb<8 ? MN : X, d = zb&7); B = base plane scaled
//        in-kernel by MTX[zb][k]. zb in [16,24): den tiles (unchanged).
__global__ __launch_bounds__(256, 2) void k_mm(
    const bf16* __restrict__ AphH, const bf16* __restrict__ AphL,
    const bf16* __restrict__ BtNh, const bf16* __restrict__ BtNl,
    const bf16* __restrict__ BtMN, const bf16* __restrict__ gxHi,
    const bf16* __restrict__ gxLo, const float* __restrict__ MTX,
    unsigned int* __restrict__ Cpk, float* __restrict__ den, int ZC,
    int zg0) {
  const size_t PA = (size_t)1024 * 2048;
  const size_t PC = (size_t)1024 * ZC;
  __shared__ __align__(16) bf16 smem[3 * 128 * 64];
  const int tid = threadIdx.x;
  const int w = tid >> 6, ln = tid & 63;
  const int fr = ln & 15, kq = (ln >> 4) * 8;
  const int cr = (ln >> 4) * 4, cc = ln & 15;
  const int zb = blockIdx.z;

  if (zb < 16) {
    // ---------------- num pair-plane (re,im packed) ----------------
    bf16(*lds)[128][64] = (bf16(*)[128][64])smem;
    const bf16* A0 = AphH + (size_t)(zb < 8 ? 0 : 2) * PA;
    const bf16* A1 = A0 + PA;
    const bf16* B =
        (zb < 8 ? BtMN : gxHi) + (size_t)zg0 * 2048;  // full-z base plane
    const float* Mrow = MTX + (size_t)zb * 2048;
    unsigned int* P = Cpk + (size_t)zb * PC;
    int bm = blockIdx.x * 128, bn = blockIdx.y * 128;
    const int r8 = ln >> 3, c8 = (ln & 7) * 8;

    f32x4 acc0[4][4], acc1[4][4];
#pragma unroll
    for (int i = 0; i < 4; i++)
#pragma unroll
      for (int j = 0; j < 4; j++) {
        acc0[i][j] = {0.f, 0.f, 0.f, 0.f};
        acc1[i][j] = {0.f, 0.f, 0.f, 0.f};
      }
    const int m0 = (w & 1) * 64, n0 = (w >> 1) * 64;

    for (int kt = 0; kt < 2048; kt += 64) {
#pragma unroll
      for (int q = 0; q < 4; ++q) {
        int row = (w * 4 + q) * 8 + r8;
        async16(A0 + (size_t)(bm + row) * 2048 + (kt + c8), &lds[0][row][c8]);
        async16(A1 + (size_t)(bm + row) * 2048 + (kt + c8), &lds[1][row][c8]);
        async16(B + (size_t)(bn + row) * 2048 + (kt + c8), &lds[2][row][c8]);
      }
      __syncthreads();
#pragma unroll
      for (int ks = 0; ks < 64; ks += 32) {
        // per-lane k-multipliers for this ks (depends on k only)
        const float4* mp = (const float4*)(Mrow + kt + ks + kq);
        float4 mA = mp[0], mB = mp[1];
        float m[8] = {mA.x, mA.y, mA.z, mA.w, mB.x, mB.y, mB.z, mB.w};
        bf16x8 a0[4], a1[4], b[4];
#pragma unroll
        for (int i = 0; i < 4; i++) {
          a0[i] = *(const bf16x8*)&lds[0][m0 + i * 16 + fr][ks + kq];
          a1[i] = *(const bf16x8*)&lds[1][m0 + i * 16 + fr][ks + kq];
          bf16x8 br = *(const bf16x8*)&lds[2][n0 + i * 16 + fr][ks + kq];
#pragma unroll
          for (int e = 0; e < 8; ++e) b[i][e] = (bf16)((float)br[e] * m[e]);
        }
#pragma unroll
        for (int i = 0; i < 4; i++)
#pragma unroll
          for (int j = 0; j < 4; j++) {
            acc0[i][j] = __builtin_amdgcn_mfma_f32_16x16x32_bf16(
                a0[i], b[j], acc0[i][j], 0, 0, 0);
            acc1[i][j] = __builtin_amdgcn_mfma_f32_16x16x32_bf16(
                a1[i], b[j], acc1[i][j], 0, 0, 0);
          }
      }
      __syncthreads();
    }
#pragma unroll
    for (int i = 0; i < 4; i++)
#pragma unroll
      for (int j = 0; j < 4; j++)
#pragma unroll
        for (int r = 0; r < 4; r++) {
          union { bf16 h[2]; unsigned int u; } pk;
          pk.h[0] = (bf16)acc0[i][j][r];
          pk.h[1] = (bf16)acc1[i][j][r];
          P[(size_t)(bm + m0 + i * 16 + cr + r) * ZC +
            (bn + n0 + j * 16 + cc)] = pk.u;
        }
  } else {
    // ---------------- den tile (split-bf16, 128x64) ----------------
    bf16(*lds)[64] = (bf16(*)[64])smem;
    int nyTiles = ZC / 64;
    int den_idx = (zb - 16) * (ZC / 128) + blockIdx.y;
    int p = den_idx / nyTiles;  // 0 denN_re,1 denN_im,2 denX_re,3 denX_im
    int ny = den_idx % nyTiles;
    int side = p >> 1, trig = p & 1;
    const bf16* Ah = AphH + (size_t)(side * 2 + trig) * PA;
    const bf16* Al = AphL + (size_t)(side * 2 + trig) * PA;
    const bf16* Bh = (side ? gxHi : BtNh) + (size_t)zg0 * 2048;
    const bf16* Bl = (side ? gxLo : BtNl) + (size_t)zg0 * 2048;
    float* C = den + (size_t)p * PC;
    int bm = blockIdx.x * 128, bn = ny * 64;
    const int r32 = tid >> 3, c8 = (tid & 7) * 8;

    f32x4 acc[4][2];
#pragma unroll
    for (int i = 0; i < 4; i++)
#pragma unroll
      for (int j = 0; j < 2; j++) acc[i][j] = {0.f, 0.f, 0.f, 0.f};
    const int m0 = (w & 1) * 64, n0 = (w >> 1) * 32;

    for (int kt = 0; kt < 2048; kt += 64) {
#pragma unroll
      for (int q = 0; q < 4; ++q) {
        int row = q * 32 + r32;
        async16(Ah + (size_t)(bm + row) * 2048 + (kt + c8), &lds[row][c8]);
        async16(Al + (size_t)(bm + row) * 2048 + (kt + c8),
                &lds[128 + row][c8]);
      }
#pragma unroll
      for (int q = 0; q < 2; ++q) {
        int row = q * 32 + r32;
        async16(Bh + (size_t)(bn + row) * 2048 + (kt + c8),
                &lds[256 + row][c8]);
        async16(Bl + (size_t)(bn + row) * 2048 + (kt + c8),
                &lds[320 + row][c8]);
      }
      __syncthreads();
#pragma unroll
      for (int ks = 0; ks < 64; ks += 32) {
        bf16x8 ah[4], alo[4], bh[2], blo[2];
#pragma unroll
        for (int i = 0; i < 4; i++) {
          ah[i]  = *(const bf16x8*)&lds[m0 + i * 16 + fr][ks + kq];
          alo[i] = *(const bf16x8*)&lds[128 + m0 + i * 16 + fr][ks + kq];
        }
#pragma unroll
        for (int j = 0; j < 2; j++) {
          bh[j]  = *(const bf16x8*)&lds[256 + n0 + j * 16 + fr][ks + kq];
          blo[j] = *(const bf16x8*)&lds[320 + n0 + j * 16 + fr][ks + kq];
        }
#pragma unroll
        for (int i = 0; i < 4; i++)
#pragma unroll
          for (int j = 0; j < 2; j++) {
            acc[i][j] = __builtin_amdgcn_mfma_f32_16x16x32_bf16(
                alo[i], bh[j], acc[i][j], 0, 0, 0);
            acc[i][j] = __builtin_amdgcn_mfma_f32_16x16x32_bf16(
                ah[i], blo[j], acc[i][j], 0, 0, 0);
            acc[i][j] = __builtin_amdgcn_mfma_f32_16x16x32_bf16(
                ah[i], bh[j], acc[i][j], 0, 0, 0);
          }
      }
      __syncthreads();
    }
#pragma unroll
    for (int i = 0; i < 4; i++)
#pragma unroll
      for (int j = 0; j < 2; j++)
#pragma unroll
        for (int r = 0; r < 4; r++) {
          size_t idx = (size_t)(bm + m0 + i * 16 + cr + r) * ZC +
                       (bn + n0 + j * 16 + cc);
          C[idx] = acc[i][j][r];
        }
  }
}

// --------------------------- final reduction -------------------------------
__device__ __forceinline__ void load8p(const unsigned int* p, float* re,
                                       float* im) {
  uint4 u0 = ((const uint4*)p)[0], u1 = ((const uint4*)p)[1];
  re[0] = __uint_as_float(u0.x << 16); im[0] = __uint_as_float(u0.x & 0xffff0000u);
  re[1] = __uint_as_float(u0.y << 16); im[1] = __uint_as_float(u0.y & 0xffff0000u);
  re[2] = __uint_as_float(u0.z << 16); im[2] = __uint_as_float(u0.z & 0xffff0000u);
  re[3] = __uint_as_float(u0.w << 16); im[3] = __uint_as_float(u0.w & 0xffff0000u);
  re[4] = __uint_as_float(u1.x << 16); im[4] = __uint_as_float(u1.x & 0xffff0000u);
  re[5] = __uint_as_float(u1.y << 16); im[5] = __uint_as_float(u1.y & 0xffff0000u);
  re[6] = __uint_as_float(u1.z << 16); im[6] = __uint_as_float(u1.z & 0xffff0000u);
  re[7] = __uint_as_float(u1.w << 16); im[7] = __uint_as_float(u1.w & 0xffff0000u);
}
__device__ __forceinline__ void load8d(const float* p, float* o) {
  float4 f0 = ((const float4*)p)[0], f1 = ((const float4*)p)[1];
  o[0] = f0.x; o[1] = f0.y; o[2] = f0.z; o[3] = f0.w;
  o[4] = f1.x; o[5] = f1.y; o[6] = f1.z; o[7] = f1.w;
}

__global__ __launch_bounds__(256) void k_reduce(
    const unsigned int* __restrict__ Cpk, const float* __restrict__ den,
    float* __restrict__ out, int ZC, int zg0) {
  const size_t PS = (size_t)1024 * ZC;
  int tid = threadIdx.x;
  int a = blockIdx.x * 2 + (tid >> 7);
  int zt = tid & 127;
  float acc = 0.f;
  for (int z = zt * 8; z < ZC; z += 1024) {
    if (zg0 + z >= 2000) break;
    size_t base = (size_t)a * ZC + z;
    float mdr[8], mdi[8], xdr[8], xdi[8], im[8], ix[8];
    load8d(den + 0 * PS + base, mdr);
    load8d(den + 1 * PS + base, mdi);
    load8d(den + 2 * PS + base, xdr);
    load8d(den + 3 * PS + base, xdi);
#pragma unroll
    for (int e = 0; e < 8; ++e) {
      im[e] = 1.f / (mdr[e] * mdr[e] + mdi[e] * mdi[e]);
      ix[e] = 1.f / (xdr[e] * xdr[e] + xdi[e] * xdi[e]);
    }
#pragma unroll
    for (int d = 0; d < 8; ++d) {
      float ar[8], ai[8], br[8], bi[8];
      load8p(Cpk + (size_t)d * PS + base, ar, ai);
      load8p(Cpk + (size_t)(8 + d) * PS + base, br, bi);
#pragma unroll
      for (int e = 0; e < 8; ++e) {
        float r1 = (ar[e] * mdr[e] + ai[e] * mdi[e]) * im[e];
        float i1 = (ai[e] * mdr[e] - ar[e] * mdi[e]) * im[e];
        float r2 = (br[e] * xdr[e] + bi[e] * xdi[e]) * ix[e];
        float i2 = (bi[e] * xdr[e] - br[e] * xdi[e]) * ix[e];
        float dr = r1 - r2, di = i1 - i2;
        acc += dr * dr + di * di;
      }
    }
  }
  for (int off = 32; off; off >>= 1) acc += __shfl_down(acc, off, 64);
  __shared__ float red[4];
  if (!(tid & 63)) red[tid >> 6] = acc;
  __syncthreads();
  if (!tid)
    atomicAdd(out,
              (red[0] + red[1] + red[2] + red[3]) * (1.f / 2000000.f));
}

// ============================================================================
extern "C" void kernel_launch(void* const* d_in, const int* in_sizes, int n_in,
                              void* d_out, int out_size, void* d_ws,
                              size_t ws_size, hipStream_t stream) {
  const float* Mm  = (const float*)d_in[0];
  const float* Nm  = (const float*)d_in[1];
  const float* Xm  = (const float*)d_in[2];
  const float* ll  = (const float*)d_in[3];
  const float* K11 = (const float*)d_in[4];
  const float* K12 = (const float*)d_in[5];
  const float* gMN = (const float*)d_in[6];
  const float* gN  = (const float*)d_in[7];
  const float* al  = (const float*)d_in[8];

  char* ws = (char*)d_ws;
  const size_t MB = 1024 * 1024;
  bf16* AphH = (bf16*)(ws);             // 16 MB
  bf16* AphL = (bf16*)(ws + 16 * MB);   // 16 MB
  bf16* gxHi = (bf16*)(ws + 32 * MB);   // 8 MB [2048][2048]
  bf16* gxLo = (bf16*)(ws + 40 * MB);   // 8 MB
  bf16* BtNh = (bf16*)(ws + 48 * MB);   // 8 MB
  bf16* BtNl = (bf16*)(ws + 56 * MB);   // 8 MB
  bf16* BtMN = (bf16*)(ws + 64 * MB);   // 8 MB
  float* MTX = (float*)(ws + 72 * MB);  // 128 KB [16][2048]
  char* chunkRgn = ws + 73 * MB;
  // transients (dead after k_gemm1), overlaid on chunk region:
  bf16* Kbf   = (bf16*)(chunkRgn);            // 8 MB
  bf16* K12T  = (bf16*)(chunkRgn + 8 * MB);   // 8 MB
  bf16* K12TL = (bf16*)(chunkRgn + 16 * MB);  // 8 MB

  // chunk: den fp32 (16384*ZC) | Cpk (65536*ZC)
  size_t avail = (ws_size > 73 * MB) ? ws_size - 73 * MB : 0;
  int ZC = 2048;
  while (ZC > 128 && (size_t)81920 * ZC > avail) ZC >>= 1;
  int NC = 2048 / ZC;
  float* denc = (float*)(chunkRgn);
  unsigned int* Cpkc = (unsigned int*)(chunkRgn + (size_t)16384 * ZC);

  k_cvt<<<dim3(3073), dim3(256), 0, stream>>>(K11, K12, Mm, Xm, Kbf, K12T,
                                              K12TL, MTX, (float*)d_out);
  k_gemm1<<<dim3(1280), dim3(256), 0, stream>>>(K12T, K12TL, Kbf, ll, al, Nm,
                                                Xm, gxHi, gxLo, AphH, AphL);
  k_prep<<<dim3(32, 32), dim3(256), 0, stream>>>(gN, gMN, BtNh, BtNl, BtMN);
  for (int c = 0; c < NC; ++c) {
    int zg0 = c * ZC;
    k_mm<<<dim3(8, ZC / 128, 24), dim3(256), 0, stream>>>(
        AphH, AphL, BtNh, BtNl, BtMN, gxHi, gxLo, MTX, Cpkc, denc, ZC, zg0);
    k_reduce<<<dim3(500), dim3(256), 0, stream>>>(Cpkc, denc, (float*)d_out,
                                                  ZC, zg0);
  }
  (void)in_sizes; (void)n_in; (void)out_size;
}

// Round 9
// 628.147 us; speedup vs baseline: 1.1222x; 1.1222x over previous
//
#include <hip/hip_runtime.h>

// ============================================================================
// XModel_66795331387584: complex phase-feature ridge loss on MI355X (gfx950)
//
// loss = mean_{a,z} sum_d | num_MN/den_MN - num_X/den_X |^2
// den path: split-bf16 (hi+lo), fp32 out (tail-dominated 1/|den|^2).
// gamma_X via 1-term Neumann: gx = (K12 - K@K12/reg)/reg (rel err 4e-6).
//
// R9: revert R8's in-loop B-scaling (VALU on MFMA critical path: 893->724 TF).
// Prebuilt 16 num planes per chunk; den reads full-z BtNh/l + gx. Merges:
// k_cvt (+gN transpose), k_big (gemm1 + phases + prepMN0), prepX0 tiny,
// k_mm (num 128x128 x2C + den 128x64 split-bf16), k_redprep (reduce c +
// prep c+1 co-dispatched). 7 dispatches @ NC=2. ws >= 233 MB (proven R8).
// ============================================================================

typedef __bf16 bf16;
typedef __bf16 bf16x8 __attribute__((ext_vector_type(8)));
typedef float f32x4 __attribute__((ext_vector_type(4)));

#define AS1 __attribute__((address_space(1)))
#define AS3 __attribute__((address_space(3)))

__device__ __forceinline__ void async16(const void* g, void* l) {
  __builtin_amdgcn_global_load_lds((AS1 const unsigned int*)g,
                                   (AS3 unsigned int*)l, 16, 0, 0);
}

// -------- shared device helpers: B-plane builders (64x64 tile) --------------
// MN planes (pl 0..7): M_d * gMN^T ; X planes (pl 8..15): X_d * gx
__device__ __forceinline__ void build_mn(const float* __restrict__ gMN,
                                         const float* __restrict__ Mm,
                                         bf16* __restrict__ Bt, int j0,
                                         int zl0, int zg0, int ZC, int tid,
                                         float (*t)[65]) {
  const size_t PL = (size_t)ZC * 2048;
  int zg = zg0 + zl0;
  for (int e = tid; e < 4096; e += 256) {
    int r = e >> 6, c = e & 63;
    t[r][c] = (j0 + r < 2000 && zg + c < 2000)
                  ? gMN[(size_t)(j0 + r) * 2000 + zg + c] : 0.f;
  }
  __syncthreads();
  const float4* M4 = (const float4*)Mm;
#pragma unroll
  for (int it = 0; it < 2; ++it) {
    int idx = it * 256 + tid;
    int zr = idx >> 3, c8 = (idx & 7) * 8;
    float g[8], mrow[8][8];
#pragma unroll
    for (int e = 0; e < 8; ++e) {
      g[e] = t[c8 + e][zr];
      int jj = j0 + c8 + e;
      if (jj < 2000) {
        float4 ma = M4[jj * 2], mb = M4[jj * 2 + 1];
        mrow[e][0] = ma.x; mrow[e][1] = ma.y; mrow[e][2] = ma.z;
        mrow[e][3] = ma.w; mrow[e][4] = mb.x; mrow[e][5] = mb.y;
        mrow[e][6] = mb.z; mrow[e][7] = mb.w;
      } else {
#pragma unroll
        for (int d = 0; d < 8; ++d) mrow[e][d] = 0.f;
      }
    }
    size_t ob = (size_t)(zl0 + zr) * 2048 + j0 + c8;
#pragma unroll
    for (int d = 0; d < 8; ++d) {
      bf16x8 v;
#pragma unroll
      for (int e = 0; e < 8; ++e) v[e] = (bf16)(g[e] * mrow[e][d]);
      *(bf16x8*)(Bt + (size_t)d * PL + ob) = v;
    }
  }
}

__device__ __forceinline__ void build_x(const bf16* __restrict__ gxHi,
                                        const bf16* __restrict__ gxLo,
                                        const float* __restrict__ Xm,
                                        bf16* __restrict__ Bt, int j0,
                                        int zl0, int zg0, int ZC, int tid) {
  const size_t PL = (size_t)ZC * 2048;
  const float4* X4 = (const float4*)Xm;
#pragma unroll
  for (int it = 0; it < 2; ++it) {
    int idx = it * 256 + tid;
    int zr = idx >> 3, c8 = (idx & 7) * 8;
    size_t gb = (size_t)(zg0 + zl0 + zr) * 2048 + j0 + c8;
    bf16x8 vh = *(const bf16x8*)(gxHi + gb);
    bf16x8 vl = *(const bf16x8*)(gxLo + gb);
    float gx[8], xr[8][8];
#pragma unroll
    for (int e = 0; e < 8; ++e) {
      gx[e] = (float)vh[e] + (float)vl[e];
      int jj = j0 + c8 + e;
      if (jj < 2000) {
        float4 xa = X4[jj * 2], xb = X4[jj * 2 + 1];
        xr[e][0] = xa.x; xr[e][1] = xa.y; xr[e][2] = xa.z; xr[e][3] = xa.w;
        xr[e][4] = xb.x; xr[e][5] = xb.y; xr[e][6] = xb.z; xr[e][7] = xb.w;
      } else {
#pragma unroll
        for (int d = 0; d < 8; ++d) xr[e][d] = 0.f;
      }
    }
    size_t ob = (size_t)(zl0 + zr) * 2048 + j0 + c8;
#pragma unroll
    for (int d = 0; d < 8; ++d) {
      bf16x8 v;
#pragma unroll
      for (int e = 0; e < 8; ++e) v[e] = (bf16)(gx[e] * xr[e][d]);
      *(bf16x8*)(Bt + (size_t)(8 + d) * PL + ob) = v;
    }
  }
}

// ---------------- k_cvt: converts + gN planes + out zero --------------------
// [0,2048): K11->Kbf | [2048,3072): K12^T->hi/lo | [3072,4096): gN^T->hi/lo
__global__ __launch_bounds__(256) void k_cvt(
    const float* __restrict__ K11, const float* __restrict__ K12,
    const float* __restrict__ gN, bf16* __restrict__ Kbf,
    bf16* __restrict__ K12T, bf16* __restrict__ K12TL,
    bf16* __restrict__ BtNh, bf16* __restrict__ BtNl,
    float* __restrict__ out) {
  __shared__ float t[64][65];
  const int bid = blockIdx.x, tid = threadIdx.x;
  if (bid < 2048) {
    if (bid == 0 && tid == 0) out[0] = 0.f;
    int e = (bid * 256 + tid) * 8;
    int j = e >> 11, k = e & 2047;
    bf16x8 v;
    if (j < 2000 && k < 2000) {
      const float4* s = (const float4*)(K11 + (size_t)j * 2000 + k);
      float4 f0 = s[0], f1 = s[1];
      v[0] = (bf16)f0.x; v[1] = (bf16)f0.y; v[2] = (bf16)f0.z; v[3] = (bf16)f0.w;
      v[4] = (bf16)f1.x; v[5] = (bf16)f1.y; v[6] = (bf16)f1.z; v[7] = (bf16)f1.w;
    } else {
      for (int i = 0; i < 8; ++i) v[i] = (bf16)0.f;
    }
    *(bf16x8*)(Kbf + e) = v;
  } else {
    bool isK12 = bid < 3072;
    const float* src = isK12 ? K12 : gN;
    bf16* dh = isK12 ? K12T : BtNh;
    bf16* dl = isK12 ? K12TL : BtNl;
    int b2 = bid - (isK12 ? 2048 : 3072);
    int j0 = (b2 & 31) * 64, z0 = (b2 >> 5) * 64;
    for (int e = tid; e < 4096; e += 256) {
      int r = e >> 6, c = e & 63;  // r=j row, c=z col
      t[r][c] = (j0 + r < 2000 && z0 + c < 2000)
                    ? src[(size_t)(j0 + r) * 2000 + z0 + c] : 0.f;
    }
    __syncthreads();
#pragma unroll
    for (int it = 0; it < 2; ++it) {
      int idx = it * 256 + tid;
      int zr = idx >> 3, c8 = (idx & 7) * 8;
      bf16x8 vh, vl;
#pragma unroll
      for (int e = 0; e < 8; ++e) {
        float g = t[c8 + e][zr];
        bf16 h = (bf16)g;
        vh[e] = h;
        vl[e] = (bf16)(g - (float)h);
      }
      size_t ob = (size_t)(z0 + zr) * 2048 + j0 + c8;
      *(bf16x8*)(dh + ob) = vh;
      *(bf16x8*)(dl + ob) = vl;
    }
  }
}

// --------- k_big: gemm1 tiles + phases + prepMN(chunk0) ---------------------
// bid<256: gamma_X tile | [256,1280): phases | >=1280: MN planes chunk 0
__global__ __launch_bounds__(256, 2) void k_big(
    const bf16* __restrict__ K12T, const bf16* __restrict__ K12TL,
    const bf16* __restrict__ Kbf, const float* __restrict__ ll,
    const float* __restrict__ al, const float* __restrict__ Nm,
    const float* __restrict__ Xm, const float* __restrict__ gMN,
    const float* __restrict__ Mm, bf16* __restrict__ gxHi,
    bf16* __restrict__ gxLo, bf16* __restrict__ AphH,
    bf16* __restrict__ AphL, bf16* __restrict__ Bt, int ZC) {
  __shared__ __align__(16) char smem[34816];
  const int tid = threadIdx.x;
  const int bid = blockIdx.x;
  if (bid >= 1280) {
    int pid = bid - 1280;
    build_mn(gMN, Mm, Bt, (pid & 31) * 64, (pid >> 5) * 64, 0, ZC, tid,
             (float(*)[65])smem);
    return;
  }
  if (bid >= 256) {
    // ---- phases: a = bid-256, 8 j per thread
    const size_t PA = (size_t)1024 * 2048;
    int a = bid - 256;
    int j0 = tid * 8;
    float vc[4][8];
    if (a < 1000) {
      const float4* A4 = (const float4*)al;
      const float4* N4 = (const float4*)Nm;
      const float4* X4 = (const float4*)Xm;
      float4 a0 = A4[a * 2], a1 = A4[a * 2 + 1];
#pragma unroll
      for (int e = 0; e < 8; ++e) {
        int j = j0 + e;
        if (j < 2000) {
          float4 n0 = N4[j * 2], n1 = N4[j * 2 + 1];
          float4 x0 = X4[j * 2], x1 = X4[j * 2 + 1];
          float pn = a0.x * n0.x + a0.y * n0.y + a0.z * n0.z + a0.w * n0.w +
                     a1.x * n1.x + a1.y * n1.y + a1.z * n1.z + a1.w * n1.w;
          float px = a0.x * x0.x + a0.y * x0.y + a0.z * x0.z + a0.w * x0.w +
                     a1.x * x1.x + a1.y * x1.y + a1.z * x1.z + a1.w * x1.w;
          __sincosf(pn, &vc[1][e], &vc[0][e]);
          __sincosf(px, &vc[3][e], &vc[2][e]);
        } else {
          vc[0][e] = vc[1][e] = vc[2][e] = vc[3][e] = 0.f;
        }
      }
    } else {
#pragma unroll
      for (int p = 0; p < 4; ++p)
#pragma unroll
        for (int e = 0; e < 8; ++e) vc[p][e] = 0.f;
    }
    size_t o = (size_t)a * 2048 + j0;
#pragma unroll
    for (int p = 0; p < 4; ++p) {
      bf16x8 vh, vl;
#pragma unroll
      for (int e = 0; e < 8; ++e) {
        bf16 h = (bf16)vc[p][e];
        vh[e] = h;
        vl[e] = (bf16)(vc[p][e] - (float)h);
      }
      *(bf16x8*)(AphH + p * PA + o) = vh;
      *(bf16x8*)(AphL + p * PA + o) = vl;
    }
    return;
  }
  // ---- gamma_X tile
  bf16(*lds)[128][64] = (bf16(*)[128][64])smem;
  int bm = (bid >> 4) * 128;  // z-tile (global)
  int bn = (bid & 15) * 128;  // j-tile
  const int w = tid >> 6, ln = tid & 63;
  const int r8 = ln >> 3, c8 = (ln & 7) * 8;
  f32x4 acc[4][4];
#pragma unroll
  for (int i = 0; i < 4; i++)
#pragma unroll
    for (int j = 0; j < 4; j++) acc[i][j] = {0.f, 0.f, 0.f, 0.f};
  const int m0 = (w & 1) * 64, n0 = (w >> 1) * 64;
  const int fr = ln & 15, kq = (ln >> 4) * 8;
  for (int kt = 0; kt < 2048; kt += 64) {
#pragma unroll
    for (int q = 0; q < 4; ++q) {
      int row = (w * 4 + q) * 8 + r8;
      async16(K12T + (size_t)(bm + row) * 2048 + (kt + c8), &lds[0][row][c8]);
      async16(Kbf + (size_t)(bn + row) * 2048 + (kt + c8), &lds[1][row][c8]);
    }
    __syncthreads();
#pragma unroll
    for (int ks = 0; ks < 64; ks += 32) {
      bf16x8 a[4], b[4];
#pragma unroll
      for (int i = 0; i < 4; i++) {
        a[i] = *(const bf16x8*)&lds[0][m0 + i * 16 + fr][ks + kq];
        b[i] = *(const bf16x8*)&lds[1][n0 + i * 16 + fr][ks + kq];
      }
#pragma unroll
      for (int i = 0; i < 4; i++)
#pragma unroll
        for (int j = 0; j < 4; j++)
          acc[i][j] = __builtin_amdgcn_mfma_f32_16x16x32_bf16(
              a[i], b[j], acc[i][j], 0, 0, 0);
    }
    __syncthreads();
  }
  float inv = 1.f / (2000.f * __expf(ll[0]));
  float* ft = (float*)smem;  // [128][68]
  const int cr = (ln >> 4) * 4, cc = ln & 15;
  const int gtid = (tid & 7) * 8;
#pragma unroll
  for (int h = 0; h < 2; ++h) {
    if ((w >> 1) == h) {
#pragma unroll
      for (int i = 0; i < 4; i++)
#pragma unroll
        for (int j = 0; j < 4; j++)
#pragma unroll
          for (int r = 0; r < 4; r++)
            ft[(m0 + i * 16 + cr + r) * 68 + j * 16 + cc] = acc[i][j][r];
    }
    __syncthreads();
    int jbase = bn + h * 64 + gtid;
#pragma unroll
    for (int it = 0; it < 4; ++it) {
      int idx = it * 256 + tid;
      int m = idx >> 3;
      int zg = bm + m;
      size_t gb = (size_t)zg * 2048 + jbase;
      bf16x8 kh = *(const bf16x8*)(K12T + gb);
      bf16x8 klo = *(const bf16x8*)(K12TL + gb);
      bf16x8 vh, vl;
#pragma unroll
      for (int e = 0; e < 8; ++e) {
        float t1 = ft[m * 68 + gtid + e];
        float gx = ((float)kh[e] + (float)klo[e] - t1 * inv) * inv;
        bf16 hh = (bf16)gx;
        vh[e] = hh;
        vl[e] = (bf16)(gx - (float)hh);
      }
      *(bf16x8*)(gxHi + gb) = vh;
      *(bf16x8*)(gxLo + gb) = vl;
    }
    __syncthreads();
  }
}

// ---------------- k_prepX: X planes for chunk 0 -----------------------------
__global__ __launch_bounds__(256) void k_prepX(
    const bf16* __restrict__ gxHi, const bf16* __restrict__ gxLo,
    const float* __restrict__ Xm, bf16* __restrict__ Bt, int ZC) {
  int pid = blockIdx.x;
  build_x(gxHi, gxLo, Xm, Bt, (pid & 31) * 64, (pid >> 5) * 64, 0, ZC,
          threadIdx.x);
}

// --------------------- unified num+den GEMM dispatch ------------------------
// zb<16: num plane zb (0-7 MN, 8-15 X), 128x128, 2 C planes (cos/sin).
// zb in [16,24): den tiles 128x64, split-bf16 3-chain, fp32 out.
__global__ __launch_bounds__(256, 2) void k_mm(
    const bf16* __restrict__ AphH, const bf16* __restrict__ AphL,
    const bf16* __restrict__ Bt, const bf16* __restrict__ BtNh,
    const bf16* __restrict__ BtNl, const bf16* __restrict__ gxHi,
    const bf16* __restrict__ gxLo, unsigned int* __restrict__ Cpk,
    float* __restrict__ den, int ZC, int zg0) {
  const size_t PA = (size_t)1024 * 2048;
  const size_t PL = (size_t)ZC * 2048;
  const size_t PC = (size_t)1024 * ZC;
  __shared__ __align__(16) bf16 smem[3 * 128 * 64];
  const int tid = threadIdx.x;
  const int w = tid >> 6, ln = tid & 63;
  const int fr = ln & 15, kq = (ln >> 4) * 8;
  const int cr = (ln >> 4) * 4, cc = ln & 15;
  const int zb = blockIdx.z;

  if (zb < 16) {
    bf16(*lds)[128][64] = (bf16(*)[128][64])smem;
    const bf16* A0 = AphH + (size_t)(zb < 8 ? 0 : 2) * PA;
    const bf16* A1 = A0 + PA;
    const bf16* B = Bt + (size_t)zb * PL;
    unsigned int* P = Cpk + (size_t)zb * PC;
    int bm = blockIdx.x * 128, bn = blockIdx.y * 128;
    const int r8 = ln >> 3, c8 = (ln & 7) * 8;

    f32x4 acc0[4][4], acc1[4][4];
#pragma unroll
    for (int i = 0; i < 4; i++)
#pragma unroll
      for (int j = 0; j < 4; j++) {
        acc0[i][j] = {0.f, 0.f, 0.f, 0.f};
        acc1[i][j] = {0.f, 0.f, 0.f, 0.f};
      }
    const int m0 = (w & 1) * 64, n0 = (w >> 1) * 64;

    for (int kt = 0; kt < 2048; kt += 64) {
#pragma unroll
      for (int q = 0; q < 4; ++q) {
        int row = (w * 4 + q) * 8 + r8;
        async16(A0 + (size_t)(bm + row) * 2048 + (kt + c8), &lds[0][row][c8]);
        async16(A1 + (size_t)(bm + row) * 2048 + (kt + c8), &lds[1][row][c8]);
        async16(B + (size_t)(bn + row) * 2048 + (kt + c8), &lds[2][row][c8]);
      }
      __syncthreads();
#pragma unroll
      for (int ks = 0; ks < 64; ks += 32) {
        bf16x8 a0[4], a1[4], b[4];
#pragma unroll
        for (int i = 0; i < 4; i++) {
          a0[i] = *(const bf16x8*)&lds[0][m0 + i * 16 + fr][ks + kq];
          a1[i] = *(const bf16x8*)&lds[1][m0 + i * 16 + fr][ks + kq];
          b[i] = *(const bf16x8*)&lds[2][n0 + i * 16 + fr][ks + kq];
        }
#pragma unroll
        for (int i = 0; i < 4; i++)
#pragma unroll
          for (int j = 0; j < 4; j++) {
            acc0[i][j] = __builtin_amdgcn_mfma_f32_16x16x32_bf16(
                a0[i], b[j], acc0[i][j], 0, 0, 0);
            acc1[i][j] = __builtin_amdgcn_mfma_f32_16x16x32_bf16(
                a1[i], b[j], acc1[i][j], 0, 0, 0);
          }
      }
      __syncthreads();
    }
#pragma unroll
    for (int i = 0; i < 4; i++)
#pragma unroll
      for (int j = 0; j < 4; j++)
#pragma unroll
        for (int r = 0; r < 4; r++) {
          union { bf16 h[2]; unsigned int u; } pk;
          pk.h[0] = (bf16)acc0[i][j][r];
          pk.h[1] = (bf16)acc1[i][j][r];
          P[(size_t)(bm + m0 + i * 16 + cr + r) * ZC +
            (bn + n0 + j * 16 + cc)] = pk.u;
        }
  } else {
    // ---------------- den tile (split-bf16, 128x64) ----------------
    bf16(*lds)[64] = (bf16(*)[64])smem;
    int nyTiles = ZC / 64;
    int den_idx = (zb - 16) * (ZC / 128) + blockIdx.y;
    int p = den_idx / nyTiles;  // 0 denN_re,1 denN_im,2 denX_re,3 denX_im
    int ny = den_idx % nyTiles;
    int side = p >> 1, trig = p & 1;
    const bf16* Ah = AphH + (size_t)(side * 2 + trig) * PA;
    const bf16* Al = AphL + (size_t)(side * 2 + trig) * PA;
    const bf16* Bh = (side ? gxHi : BtNh) + (size_t)zg0 * 2048;
    const bf16* Bl = (side ? gxLo : BtNl) + (size_t)zg0 * 2048;
    float* C = den + (size_t)p * PC;
    int bm = blockIdx.x * 128, bn = ny * 64;
    const int r32 = tid >> 3, c8 = (tid & 7) * 8;

    f32x4 acc[4][2];
#pragma unroll
    for (int i = 0; i < 4; i++)
#pragma unroll
      for (int j = 0; j < 2; j++) acc[i][j] = {0.f, 0.f, 0.f, 0.f};
    const int m0 = (w & 1) * 64, n0 = (w >> 1) * 32;

    for (int kt = 0; kt < 2048; kt += 64) {
#pragma unroll
      for (int q = 0; q < 4; ++q) {
        int row = q * 32 + r32;
        async16(Ah + (size_t)(bm + row) * 2048 + (kt + c8), &lds[row][c8]);
        async16(Al + (size_t)(bm + row) * 2048 + (kt + c8),
                &lds[128 + row][c8]);
      }
#pragma unroll
      for (int q = 0; q < 2; ++q) {
        int row = q * 32 + r32;
        async16(Bh + (size_t)(bn + row) * 2048 + (kt + c8),
                &lds[256 + row][c8]);
        async16(Bl + (size_t)(bn + row) * 2048 + (kt + c8),
                &lds[320 + row][c8]);
      }
      __syncthreads();
#pragma unroll
      for (int ks = 0; ks < 64; ks += 32) {
        bf16x8 ah[4], alo[4], bh[2], blo[2];
#pragma unroll
        for (int i = 0; i < 4; i++) {
          ah[i]  = *(const bf16x8*)&lds[m0 + i * 16 + fr][ks + kq];
          alo[i] = *(const bf16x8*)&lds[128 + m0 + i * 16 + fr][ks + kq];
        }
#pragma unroll
        for (int j = 0; j < 2; j++) {
          bh[j]  = *(const bf16x8*)&lds[256 + n0 + j * 16 + fr][ks + kq];
          blo[j] = *(const bf16x8*)&lds[320 + n0 + j * 16 + fr][ks + kq];
        }
#pragma unroll
        for (int i = 0; i < 4; i++)
#pragma unroll
          for (int j = 0; j < 2; j++) {
            acc[i][j] = __builtin_amdgcn_mfma_f32_16x16x32_bf16(
                alo[i], bh[j], acc[i][j], 0, 0, 0);
            acc[i][j] = __builtin_amdgcn_mfma_f32_16x16x32_bf16(
                ah[i], blo[j], acc[i][j], 0, 0, 0);
            acc[i][j] = __builtin_amdgcn_mfma_f32_16x16x32_bf16(
                ah[i], bh[j], acc[i][j], 0, 0, 0);
          }
      }
      __syncthreads();
    }
#pragma unroll
    for (int i = 0; i < 4; i++)
#pragma unroll
      for (int j = 0; j < 2; j++)
#pragma unroll
        for (int r = 0; r < 4; r++) {
          size_t idx = (size_t)(bm + m0 + i * 16 + cr + r) * ZC +
                       (bn + n0 + j * 16 + cc);
          C[idx] = acc[i][j][r];
        }
  }
}

// ------------- k_redprep: reduce chunk c (+ prep chunk c+1) -----------------
__device__ __forceinline__ void load8p(const unsigned int* p, float* re,
                                       float* im) {
  uint4 u0 = ((const uint4*)p)[0], u1 = ((const uint4*)p)[1];
  re[0] = __uint_as_float(u0.x << 16); im[0] = __uint_as_float(u0.x & 0xffff0000u);
  re[1] = __uint_as_float(u0.y << 16); im[1] = __uint_as_float(u0.y & 0xffff0000u);
  re[2] = __uint_as_float(u0.z << 16); im[2] = __uint_as_float(u0.z & 0xffff0000u);
  re[3] = __uint_as_float(u0.w << 16); im[3] = __uint_as_float(u0.w & 0xffff0000u);
  re[4] = __uint_as_float(u1.x << 16); im[4] = __uint_as_float(u1.x & 0xffff0000u);
  re[5] = __uint_as_float(u1.y << 16); im[5] = __uint_as_float(u1.y & 0xffff0000u);
  re[6] = __uint_as_float(u1.z << 16); im[6] = __uint_as_float(u1.z & 0xffff0000u);
  re[7] = __uint_as_float(u1.w << 16); im[7] = __uint_as_float(u1.w & 0xffff0000u);
}
__device__ __forceinline__ void load8d(const float* p, float* o) {
  float4 f0 = ((const float4*)p)[0], f1 = ((const float4*)p)[1];
  o[0] = f0.x; o[1] = f0.y; o[2] = f0.z; o[3] = f0.w;
  o[4] = f1.x; o[5] = f1.y; o[6] = f1.z; o[7] = f1.w;
}

__global__ __launch_bounds__(256) void k_redprep(
    const unsigned int* __restrict__ Cpk, const float* __restrict__ den,
    float* __restrict__ out, const float* __restrict__ gMN,
    const float* __restrict__ Mm, const bf16* __restrict__ gxHi,
    const bf16* __restrict__ gxLo, const float* __restrict__ Xm,
    bf16* __restrict__ BtNext, int ZC, int zg0) {
  __shared__ float sm[64][65];
  const int bid = blockIdx.x, tid = threadIdx.x;
  if (bid >= 500) {
    // prep chunk c+1 (both plane sets)
    int pid = bid - 500;
    int j0 = (pid & 31) * 64, zl0 = (pid >> 5) * 64;
    int zg0n = zg0 + ZC;
    build_mn(gMN, Mm, BtNext, j0, zl0, zg0n, ZC, tid, sm);
    build_x(gxHi, gxLo, Xm, BtNext, j0, zl0, zg0n, ZC, tid);
    return;
  }
  const size_t PS = (size_t)1024 * ZC;
  int a = bid * 2 + (tid >> 7);
  int zt = tid & 127;
  float acc = 0.f;
  for (int z = zt * 8; z < ZC; z += 1024) {
    if (zg0 + z >= 2000) break;
    size_t base = (size_t)a * ZC + z;
    float mdr[8], mdi[8], xdr[8], xdi[8], im[8], ix[8];
    load8d(den + 0 * PS + base, mdr);
    load8d(den + 1 * PS + base, mdi);
    load8d(den + 2 * PS + base, xdr);
    load8d(den + 3 * PS + base, xdi);
#pragma unroll
    for (int e = 0; e < 8; ++e) {
      im[e] = 1.f / (mdr[e] * mdr[e] + mdi[e] * mdi[e]);
      ix[e] = 1.f / (xdr[e] * xdr[e] + xdi[e] * xdi[e]);
    }
#pragma unroll
    for (int d = 0; d < 8; ++d) {
      float ar[8], ai[8], br[8], bi[8];
      load8p(Cpk + (size_t)d * PS + base, ar, ai);
      load8p(Cpk + (size_t)(8 + d) * PS + base, br, bi);
#pragma unroll
      for (int e = 0; e < 8; ++e) {
        float r1 = (ar[e] * mdr[e] + ai[e] * mdi[e]) * im[e];
        float i1 = (ai[e] * mdr[e] - ar[e] * mdi[e]) * im[e];
        float r2 = (br[e] * xdr[e] + bi[e] * xdi[e]) * ix[e];
        float i2 = (bi[e] * xdr[e] - br[e] * xdi[e]) * ix[e];
        float dr = r1 - r2, di = i1 - i2;
        acc += dr * dr + di * di;
      }
    }
  }
  for (int off = 32; off; off >>= 1) acc += __shfl_down(acc, off, 64);
  __shared__ float red[4];
  if (!(tid & 63)) red[tid >> 6] = acc;
  __syncthreads();
  if (!tid)
    atomicAdd(out, (red[0] + red[1] + red[2] + red[3]) * (1.f / 2000000.f));
}

// ============================================================================
extern "C" void kernel_launch(void* const* d_in, const int* in_sizes, int n_in,
                              void* d_out, int out_size, void* d_ws,
                              size_t ws_size, hipStream_t stream) {
  const float* Mm  = (const float*)d_in[0];
  const float* Nm  = (const float*)d_in[1];
  const float* Xm  = (const float*)d_in[2];
  const float* ll  = (const float*)d_in[3];
  const float* K11 = (const float*)d_in[4];
  const float* K12 = (const float*)d_in[5];
  const float* gMN = (const float*)d_in[6];
  const float* gN  = (const float*)d_in[7];
  const float* al  = (const float*)d_in[8];

  char* ws = (char*)d_ws;
  const size_t MB = 1024 * 1024;
  bf16* AphH = (bf16*)(ws);             // 16 MB
  bf16* AphL = (bf16*)(ws + 16 * MB);   // 16 MB
  bf16* gxHi = (bf16*)(ws + 32 * MB);   // 8 MB
  bf16* gxLo = (bf16*)(ws + 40 * MB);   // 8 MB
  bf16* BtNh = (bf16*)(ws + 48 * MB);   // 8 MB (gN^T hi, full z)
  bf16* BtNl = (bf16*)(ws + 56 * MB);   // 8 MB
  char* chunkRgn = ws + 64 * MB;

  // chunk: Bt 16 planes (65536*ZC) | den (16384*ZC) | Cpk (65536*ZC)
  // transients (Kbf/K12T/K12TL, 24 MB) live after the chunk region.
  size_t avail = (ws_size > 88 * MB) ? ws_size - 88 * MB : 0;
  int ZC = 2048;
  while (ZC > 128 && (size_t)147456 * ZC > avail) ZC >>= 1;
  int NC = 2048 / ZC;
  bf16* Btc = (bf16*)(chunkRgn);
  float* denc = (float*)(chunkRgn + (size_t)65536 * ZC);
  unsigned int* Cpkc = (unsigned int*)(chunkRgn + (size_t)81920 * ZC);
  char* trans = chunkRgn + (size_t)147456 * ZC;
  bf16* Kbf   = (bf16*)(trans);
  bf16* K12T  = (bf16*)(trans + 8 * MB);
  bf16* K12TL = (bf16*)(trans + 16 * MB);

  int NBP = 32 * (ZC / 64);  // prep blocks per chunk

  k_cvt<<<dim3(4096), dim3(256), 0, stream>>>(K11, K12, gN, Kbf, K12T, K12TL,
                                              BtNh, BtNl, (float*)d_out);
  k_big<<<dim3(1280 + NBP), dim3(256), 0, stream>>>(
      K12T, K12TL, Kbf, ll, al, Nm, Xm, gMN, Mm, gxHi, gxLo, AphH, AphL, Btc,
      ZC);
  k_prepX<<<dim3(NBP), dim3(256), 0, stream>>>(gxHi, gxLo, Xm, Btc, ZC);
  for (int c = 0; c < NC; ++c) {
    int zg0 = c * ZC;
    k_mm<<<dim3(8, ZC / 128, 24), dim3(256), 0, stream>>>(
        AphH, AphL, Btc, BtNh, BtNl, gxHi, gxLo, Cpkc, denc, ZC, zg0);
    int nblk = (c + 1 < NC) ? 500 + NBP : 500;
    k_redprep<<<dim3(nblk), dim3(256), 0, stream>>>(
        Cpkc, denc, (float*)d_out, gMN, Mm, gxHi, gxLo, Xm, Btc, ZC, zg0);
  }
  (void)in_sizes; (void)n_in; (void)out_size;
}

// Round 10
// 523.884 us; speedup vs baseline: 1.3455x; 1.1990x over previous
//
#include <hip/hip_runtime.h>

// ============================================================================
// XModel_66795331387584: complex phase-feature ridge loss on MI355X (gfx950)
//
// loss = mean_{a,z} sum_d | num_MN/den_MN - num_X/den_X |^2
// den path: split-bf16 (hi+lo), fp32 out (tail-dominated 1/|den|^2).
// gamma_X via 1-term Neumann: gx = (K12 - K@K12/reg)/reg (rel err 4e-6).
//
// R10: num GEMM moves to MX-fp8 (mfma_scale_f32_16x16x128_f8f6f4, uniform
// E8M0 scales: A=1.0, B=2^-6 (MN, stored x64) / 2^-13 (X, stored x8192)).
// K-layout safety: same (lane-group,byte)->k map for A and B => dot product
// invariant. Den stays split-bf16 (precision). B planes now fp8 (32 MB/chunk).
// ============================================================================

typedef __bf16 bf16;
typedef __bf16 bf16x8 __attribute__((ext_vector_type(8)));
typedef float f32x4 __attribute__((ext_vector_type(4)));
typedef int i32x8 __attribute__((ext_vector_type(8)));

#define AS1 __attribute__((address_space(1)))
#define AS3 __attribute__((address_space(3)))

__device__ __forceinline__ void async16(const void* g, void* l) {
  __builtin_amdgcn_global_load_lds((AS1 const unsigned int*)g,
                                   (AS3 unsigned int*)l, 16, 0, 0);
}

__device__ __forceinline__ unsigned int pk4f8(float a, float b, float c,
                                              float d) {
  int w = __builtin_amdgcn_cvt_pk_fp8_f32(a, b, 0, false);
  w = __builtin_amdgcn_cvt_pk_fp8_f32(c, d, w, true);
  return (unsigned int)w;
}

// -------- B-plane builders (fp8, 64x64 tile) --------------------------------
// planes 0..7: 64 * M_d * gMN^T ; planes 8..15: 8192 * X_d * gx
__device__ __forceinline__ void build_mn(const float* __restrict__ gMN,
                                         const float* __restrict__ Mm,
                                         unsigned char* __restrict__ B8,
                                         int j0, int zl0, int zg0, int ZC,
                                         int tid, float (*t)[65]) {
  const size_t PL = (size_t)ZC * 2048;
  int zg = zg0 + zl0;
  for (int e = tid; e < 4096; e += 256) {
    int r = e >> 6, c = e & 63;
    t[r][c] = (j0 + r < 2000 && zg + c < 2000)
                  ? gMN[(size_t)(j0 + r) * 2000 + zg + c] : 0.f;
  }
  __syncthreads();
  const float4* M4 = (const float4*)Mm;
#pragma unroll
  for (int it = 0; it < 2; ++it) {
    int idx = it * 256 + tid;
    int zr = idx >> 3, c8 = (idx & 7) * 8;
    float g[8], mrow[8][8];
#pragma unroll
    for (int e = 0; e < 8; ++e) {
      g[e] = 64.f * t[c8 + e][zr];
      int jj = j0 + c8 + e;
      if (jj < 2000) {
        float4 ma = M4[jj * 2], mb = M4[jj * 2 + 1];
        mrow[e][0] = ma.x; mrow[e][1] = ma.y; mrow[e][2] = ma.z;
        mrow[e][3] = ma.w; mrow[e][4] = mb.x; mrow[e][5] = mb.y;
        mrow[e][6] = mb.z; mrow[e][7] = mb.w;
      } else {
#pragma unroll
        for (int d = 0; d < 8; ++d) mrow[e][d] = 0.f;
      }
    }
    size_t ob = (size_t)(zl0 + zr) * 2048 + j0 + c8;
#pragma unroll
    for (int d = 0; d < 8; ++d) {
      uint2 u;
      u.x = pk4f8(g[0] * mrow[0][d], g[1] * mrow[1][d], g[2] * mrow[2][d],
                  g[3] * mrow[3][d]);
      u.y = pk4f8(g[4] * mrow[4][d], g[5] * mrow[5][d], g[6] * mrow[6][d],
                  g[7] * mrow[7][d]);
      *(uint2*)(B8 + (size_t)d * PL + ob) = u;
    }
  }
}

__device__ __forceinline__ void build_x(const bf16* __restrict__ gxHi,
                                        const bf16* __restrict__ gxLo,
                                        const float* __restrict__ Xm,
                                        unsigned char* __restrict__ B8,
                                        int j0, int zl0, int zg0, int ZC,
                                        int tid) {
  const size_t PL = (size_t)ZC * 2048;
  const float4* X4 = (const float4*)Xm;
#pragma unroll
  for (int it = 0; it < 2; ++it) {
    int idx = it * 256 + tid;
    int zr = idx >> 3, c8 = (idx & 7) * 8;
    size_t gb = (size_t)(zg0 + zl0 + zr) * 2048 + j0 + c8;
    bf16x8 vh = *(const bf16x8*)(gxHi + gb);
    bf16x8 vl = *(const bf16x8*)(gxLo + gb);
    float gx[8], xr[8][8];
#pragma unroll
    for (int e = 0; e < 8; ++e) {
      gx[e] = 8192.f * ((float)vh[e] + (float)vl[e]);
      int jj = j0 + c8 + e;
      if (jj < 2000) {
        float4 xa = X4[jj * 2], xb = X4[jj * 2 + 1];
        xr[e][0] = xa.x; xr[e][1] = xa.y; xr[e][2] = xa.z; xr[e][3] = xa.w;
        xr[e][4] = xb.x; xr[e][5] = xb.y; xr[e][6] = xb.z; xr[e][7] = xb.w;
      } else {
#pragma unroll
        for (int d = 0; d < 8; ++d) xr[e][d] = 0.f;
      }
    }
    size_t ob = (size_t)(zl0 + zr) * 2048 + j0 + c8;
#pragma unroll
    for (int d = 0; d < 8; ++d) {
      uint2 u;
      u.x = pk4f8(gx[0] * xr[0][d], gx[1] * xr[1][d], gx[2] * xr[2][d],
                  gx[3] * xr[3][d]);
      u.y = pk4f8(gx[4] * xr[4][d], gx[5] * xr[5][d], gx[6] * xr[6][d],
                  gx[7] * xr[7][d]);
      *(uint2*)(B8 + (size_t)(8 + d) * PL + ob) = u;
    }
  }
}

// ---------------- k_cvt: converts + gN planes + out zero --------------------
__global__ __launch_bounds__(256) void k_cvt(
    const float* __restrict__ K11, const float* __restrict__ K12,
    const float* __restrict__ gN, bf16* __restrict__ Kbf,
    bf16* __restrict__ K12T, bf16* __restrict__ K12TL,
    bf16* __restrict__ BtNh, bf16* __restrict__ BtNl,
    float* __restrict__ out) {
  __shared__ float t[64][65];
  const int bid = blockIdx.x, tid = threadIdx.x;
  if (bid < 2048) {
    if (bid == 0 && tid == 0) out[0] = 0.f;
    int e = (bid * 256 + tid) * 8;
    int j = e >> 11, k = e & 2047;
    bf16x8 v;
    if (j < 2000 && k < 2000) {
      const float4* s = (const float4*)(K11 + (size_t)j * 2000 + k);
      float4 f0 = s[0], f1 = s[1];
      v[0] = (bf16)f0.x; v[1] = (bf16)f0.y; v[2] = (bf16)f0.z; v[3] = (bf16)f0.w;
      v[4] = (bf16)f1.x; v[5] = (bf16)f1.y; v[6] = (bf16)f1.z; v[7] = (bf16)f1.w;
    } else {
      for (int i = 0; i < 8; ++i) v[i] = (bf16)0.f;
    }
    *(bf16x8*)(Kbf + e) = v;
  } else {
    bool isK12 = bid < 3072;
    const float* src = isK12 ? K12 : gN;
    bf16* dh = isK12 ? K12T : BtNh;
    bf16* dl = isK12 ? K12TL : BtNl;
    int b2 = bid - (isK12 ? 2048 : 3072);
    int j0 = (b2 & 31) * 64, z0 = (b2 >> 5) * 64;
    for (int e = tid; e < 4096; e += 256) {
      int r = e >> 6, c = e & 63;
      t[r][c] = (j0 + r < 2000 && z0 + c < 2000)
                    ? src[(size_t)(j0 + r) * 2000 + z0 + c] : 0.f;
    }
    __syncthreads();
#pragma unroll
    for (int it = 0; it < 2; ++it) {
      int idx = it * 256 + tid;
      int zr = idx >> 3, c8 = (idx & 7) * 8;
      bf16x8 vh, vl;
#pragma unroll
      for (int e = 0; e < 8; ++e) {
        float g = t[c8 + e][zr];
        bf16 h = (bf16)g;
        vh[e] = h;
        vl[e] = (bf16)(g - (float)h);
      }
      size_t ob = (size_t)(z0 + zr) * 2048 + j0 + c8;
      *(bf16x8*)(dh + ob) = vh;
      *(bf16x8*)(dl + ob) = vl;
    }
  }
}

// --------- k_big: gemm1 tiles + phases (+fp8) + prepMN(chunk0) --------------
__global__ __launch_bounds__(256, 2) void k_big(
    const bf16* __restrict__ K12T, const bf16* __restrict__ K12TL,
    const bf16* __restrict__ Kbf, const float* __restrict__ ll,
    const float* __restrict__ al, const float* __restrict__ Nm,
    const float* __restrict__ Xm, const float* __restrict__ gMN,
    const float* __restrict__ Mm, bf16* __restrict__ gxHi,
    bf16* __restrict__ gxLo, bf16* __restrict__ AphH,
    bf16* __restrict__ AphL, unsigned char* __restrict__ Aph8,
    unsigned char* __restrict__ B8, int ZC) {
  __shared__ __align__(16) char smem[34816];
  const int tid = threadIdx.x;
  const int bid = blockIdx.x;
  if (bid >= 1280) {
    int pid = bid - 1280;
    build_mn(gMN, Mm, B8, (pid & 31) * 64, (pid >> 5) * 64, 0, ZC, tid,
             (float(*)[65])smem);
    return;
  }
  if (bid >= 256) {
    // ---- phases: a = bid-256, 8 j per thread
    const size_t PA = (size_t)1024 * 2048;
    int a = bid - 256;
    int j0 = tid * 8;
    float vc[4][8];
    if (a < 1000) {
      const float4* A4 = (const float4*)al;
      const float4* N4 = (const float4*)Nm;
      const float4* X4 = (const float4*)Xm;
      float4 a0 = A4[a * 2], a1 = A4[a * 2 + 1];
#pragma unroll
      for (int e = 0; e < 8; ++e) {
        int j = j0 + e;
        if (j < 2000) {
          float4 n0 = N4[j * 2], n1 = N4[j * 2 + 1];
          float4 x0 = X4[j * 2], x1 = X4[j * 2 + 1];
          float pn = a0.x * n0.x + a0.y * n0.y + a0.z * n0.z + a0.w * n0.w +
                     a1.x * n1.x + a1.y * n1.y + a1.z * n1.z + a1.w * n1.w;
          float px = a0.x * x0.x + a0.y * x0.y + a0.z * x0.z + a0.w * x0.w +
                     a1.x * x1.x + a1.y * x1.y + a1.z * x1.z + a1.w * x1.w;
          __sincosf(pn, &vc[1][e], &vc[0][e]);
          __sincosf(px, &vc[3][e], &vc[2][e]);
        } else {
          vc[0][e] = vc[1][e] = vc[2][e] = vc[3][e] = 0.f;
        }
      }
    } else {
#pragma unroll
      for (int p = 0; p < 4; ++p)
#pragma unroll
        for (int e = 0; e < 8; ++e) vc[p][e] = 0.f;
    }
    size_t o = (size_t)a * 2048 + j0;
#pragma unroll
    for (int p = 0; p < 4; ++p) {
      bf16x8 vh, vl;
#pragma unroll
      for (int e = 0; e < 8; ++e) {
        bf16 h = (bf16)vc[p][e];
        vh[e] = h;
        vl[e] = (bf16)(vc[p][e] - (float)h);
      }
      *(bf16x8*)(AphH + p * PA + o) = vh;
      *(bf16x8*)(AphL + p * PA + o) = vl;
      uint2 u8;
      u8.x = pk4f8(vc[p][0], vc[p][1], vc[p][2], vc[p][3]);
      u8.y = pk4f8(vc[p][4], vc[p][5], vc[p][6], vc[p][7]);
      *(uint2*)(Aph8 + p * PA + o) = u8;
    }
    return;
  }
  // ---- gamma_X tile
  bf16(*lds)[128][64] = (bf16(*)[128][64])smem;
  int bm = (bid >> 4) * 128;
  int bn = (bid & 15) * 128;
  const int w = tid >> 6, ln = tid & 63;
  const int r8 = ln >> 3, c8 = (ln & 7) * 8;
  f32x4 acc[4][4];
#pragma unroll
  for (int i = 0; i < 4; i++)
#pragma unroll
    for (int j = 0; j < 4; j++) acc[i][j] = {0.f, 0.f, 0.f, 0.f};
  const int m0 = (w & 1) * 64, n0 = (w >> 1) * 64;
  const int fr = ln & 15, kq = (ln >> 4) * 8;
  for (int kt = 0; kt < 2048; kt += 64) {
#pragma unroll
    for (int q = 0; q < 4; ++q) {
      int row = (w * 4 + q) * 8 + r8;
      async16(K12T + (size_t)(bm + row) * 2048 + (kt + c8), &lds[0][row][c8]);
      async16(Kbf + (size_t)(bn + row) * 2048 + (kt + c8), &lds[1][row][c8]);
    }
    __syncthreads();
#pragma unroll
    for (int ks = 0; ks < 64; ks += 32) {
      bf16x8 a[4], b[4];
#pragma unroll
      for (int i = 0; i < 4; i++) {
        a[i] = *(const bf16x8*)&lds[0][m0 + i * 16 + fr][ks + kq];
        b[i] = *(const bf16x8*)&lds[1][n0 + i * 16 + fr][ks + kq];
      }
#pragma unroll
      for (int i = 0; i < 4; i++)
#pragma unroll
        for (int j = 0; j < 4; j++)
          acc[i][j] = __builtin_amdgcn_mfma_f32_16x16x32_bf16(
              a[i], b[j], acc[i][j], 0, 0, 0);
    }
    __syncthreads();
  }
  float inv = 1.f / (2000.f * __expf(ll[0]));
  float* ft = (float*)smem;  // [128][68]
  const int cr = (ln >> 4) * 4, cc = ln & 15;
  const int gtid = (tid & 7) * 8;
#pragma unroll
  for (int h = 0; h < 2; ++h) {
    if ((w >> 1) == h) {
#pragma unroll
      for (int i = 0; i < 4; i++)
#pragma unroll
        for (int j = 0; j < 4; j++)
#pragma unroll
          for (int r = 0; r < 4; r++)
            ft[(m0 + i * 16 + cr + r) * 68 + j * 16 + cc] = acc[i][j][r];
    }
    __syncthreads();
    int jbase = bn + h * 64 + gtid;
#pragma unroll
    for (int it = 0; it < 4; ++it) {
      int idx = it * 256 + tid;
      int m = idx >> 3;
      int zg = bm + m;
      size_t gb = (size_t)zg * 2048 + jbase;
      bf16x8 kh = *(const bf16x8*)(K12T + gb);
      bf16x8 klo = *(const bf16x8*)(K12TL + gb);
      bf16x8 vh, vl;
#pragma unroll
      for (int e = 0; e < 8; ++e) {
        float t1 = ft[m * 68 + gtid + e];
        float gx = ((float)kh[e] + (float)klo[e] - t1 * inv) * inv;
        bf16 hh = (bf16)gx;
        vh[e] = hh;
        vl[e] = (bf16)(gx - (float)hh);
      }
      *(bf16x8*)(gxHi + gb) = vh;
      *(bf16x8*)(gxLo + gb) = vl;
    }
    __syncthreads();
  }
}

// ---------------- k_prepX: X planes for chunk 0 -----------------------------
__global__ __launch_bounds__(256) void k_prepX(
    const bf16* __restrict__ gxHi, const bf16* __restrict__ gxLo,
    const float* __restrict__ Xm, unsigned char* __restrict__ B8, int ZC) {
  int pid = blockIdx.x;
  build_x(gxHi, gxLo, Xm, B8, (pid & 31) * 64, (pid >> 5) * 64, 0, ZC,
          threadIdx.x);
}

// --------------------- unified num(fp8)+den(bf16) GEMM ----------------------
// zb<16: num plane zb via mfma_scale 16x16x128 fp8 (A=Aph8, B=B8 plane zb),
//        uniform scales A=1.0, B=2^-6 (zb<8) / 2^-13 (zb>=8).
// zb in [16,24): den tiles 128x64 split-bf16 3-chain, fp32 out.
__global__ __launch_bounds__(256, 2) void k_mm(
    const bf16* __restrict__ AphH, const bf16* __restrict__ AphL,
    const unsigned char* __restrict__ Aph8,
    const unsigned char* __restrict__ B8, const bf16* __restrict__ BtNh,
    const bf16* __restrict__ BtNl, const bf16* __restrict__ gxHi,
    const bf16* __restrict__ gxLo, unsigned int* __restrict__ Cpk,
    float* __restrict__ den, int ZC, int zg0) {
  const size_t PA = (size_t)1024 * 2048;
  const size_t PL8 = (size_t)ZC * 2048;  // bytes per fp8 plane
  const size_t PC = (size_t)1024 * ZC;
  __shared__ __align__(16) bf16 smem[3 * 128 * 64];  // 48 KB
  const int tid = threadIdx.x;
  const int w = tid >> 6, ln = tid & 63;
  const int fr = ln & 15;
  const int cr = (ln >> 4) * 4, cc = ln & 15;
  const int zb = blockIdx.z;

  if (zb < 16) {
    // ---------------- num pair-plane, fp8 K=128 ----------------
    unsigned char* l8 = (unsigned char*)smem;  // 3 planes x [128][128] bytes
    const unsigned char* A0 = Aph8 + (size_t)(zb < 8 ? 0 : 2) * PA;
    const unsigned char* A1 = A0 + PA;
    const unsigned char* B = B8 + (size_t)zb * PL8;
    const int sb = (zb < 8) ? 0x79797979 : 0x72727272;  // 2^-6 / 2^-13
    unsigned int* P = Cpk + (size_t)zb * PC;
    int bm = blockIdx.x * 128, bn = blockIdx.y * 128;
    const int colb = (ln & 7) * 16;  // byte col for staging
    const int kg = (ln >> 4) * 32;   // k-byte group for frags

    f32x4 acc0[4][4], acc1[4][4];
#pragma unroll
    for (int i = 0; i < 4; i++)
#pragma unroll
      for (int j = 0; j < 4; j++) {
        acc0[i][j] = {0.f, 0.f, 0.f, 0.f};
        acc1[i][j] = {0.f, 0.f, 0.f, 0.f};
      }
    const int m0 = (w & 1) * 64, n0 = (w >> 1) * 64;

    for (int kt = 0; kt < 2048; kt += 128) {
#pragma unroll
      for (int q = 0; q < 4; ++q) {
        int row = w * 32 + q * 8 + (ln >> 3);
        async16(A0 + (size_t)(bm + row) * 2048 + kt + colb,
                l8 + row * 128 + colb);
        async16(A1 + (size_t)(bm + row) * 2048 + kt + colb,
                l8 + 16384 + row * 128 + colb);
        async16(B + (size_t)(bn + row) * 2048 + kt + colb,
                l8 + 32768 + row * 128 + colb);
      }
      __syncthreads();
      i32x8 a0[4], a1[4];
#pragma unroll
      for (int i = 0; i < 4; i++) {
        a0[i] = *(const i32x8*)(l8 + (m0 + i * 16 + fr) * 128 + kg);
        a1[i] = *(const i32x8*)(l8 + 16384 + (m0 + i * 16 + fr) * 128 + kg);
      }
#pragma unroll
      for (int j = 0; j < 4; ++j) {
        i32x8 bf = *(const i32x8*)(l8 + 32768 + (n0 + j * 16 + fr) * 128 + kg);
#pragma unroll
        for (int i = 0; i < 4; ++i) {
          acc0[i][j] = __builtin_amdgcn_mfma_scale_f32_16x16x128_f8f6f4(
              a0[i], bf, acc0[i][j], 0, 0, 0, 0x7F7F7F7F, 0, sb);
          acc1[i][j] = __builtin_amdgcn_mfma_scale_f32_16x16x128_f8f6f4(
              a1[i], bf, acc1[i][j], 0, 0, 0, 0x7F7F7F7F, 0, sb);
        }
      }
      __syncthreads();
    }
#pragma unroll
    for (int i = 0; i < 4; i++)
#pragma unroll
      for (int j = 0; j < 4; j++)
#pragma unroll
        for (int r = 0; r < 4; r++) {
          union { bf16 h[2]; unsigned int u; } pk;
          pk.h[0] = (bf16)acc0[i][j][r];
          pk.h[1] = (bf16)acc1[i][j][r];
          P[(size_t)(bm + m0 + i * 16 + cr + r) * ZC +
            (bn + n0 + j * 16 + cc)] = pk.u;
        }
  } else {
    // ---------------- den tile (split-bf16, 128x64) ----------------
    bf16(*lds)[64] = (bf16(*)[64])smem;
    const int kq = (ln >> 4) * 8;
    int nyTiles = ZC / 64;
    int den_idx = (zb - 16) * (ZC / 128) + blockIdx.y;
    int p = den_idx / nyTiles;
    int ny = den_idx % nyTiles;
    int side = p >> 1, trig = p & 1;
    const bf16* Ah = AphH + (size_t)(side * 2 + trig) * PA;
    const bf16* Al = AphL + (size_t)(side * 2 + trig) * PA;
    const bf16* Bh = (side ? gxHi : BtNh) + (size_t)zg0 * 2048;
    const bf16* Bl = (side ? gxLo : BtNl) + (size_t)zg0 * 2048;
    float* C = den + (size_t)p * PC;
    int bm = blockIdx.x * 128, bn = ny * 64;
    const int r32 = tid >> 3, c8 = (tid & 7) * 8;

    f32x4 acc[4][2];
#pragma unroll
    for (int i = 0; i < 4; i++)
#pragma unroll
      for (int j = 0; j < 2; j++) acc[i][j] = {0.f, 0.f, 0.f, 0.f};
    const int m0 = (w & 1) * 64, n0 = (w >> 1) * 32;

    for (int kt = 0; kt < 2048; kt += 64) {
#pragma unroll
      for (int q = 0; q < 4; ++q) {
        int row = q * 32 + r32;
        async16(Ah + (size_t)(bm + row) * 2048 + (kt + c8), &lds[row][c8]);
        async16(Al + (size_t)(bm + row) * 2048 + (kt + c8),
                &lds[128 + row][c8]);
      }
#pragma unroll
      for (int q = 0; q < 2; ++q) {
        int row = q * 32 + r32;
        async16(Bh + (size_t)(bn + row) * 2048 + (kt + c8),
                &lds[256 + row][c8]);
        async16(Bl + (size_t)(bn + row) * 2048 + (kt + c8),
                &lds[320 + row][c8]);
      }
      __syncthreads();
#pragma unroll
      for (int ks = 0; ks < 64; ks += 32) {
        bf16x8 ah[4], alo[4], bh[2], blo[2];
#pragma unroll
        for (int i = 0; i < 4; i++) {
          ah[i]  = *(const bf16x8*)&lds[m0 + i * 16 + fr][ks + kq];
          alo[i] = *(const bf16x8*)&lds[128 + m0 + i * 16 + fr][ks + kq];
        }
#pragma unroll
        for (int j = 0; j < 2; j++) {
          bh[j]  = *(const bf16x8*)&lds[256 + n0 + j * 16 + fr][ks + kq];
          blo[j] = *(const bf16x8*)&lds[320 + n0 + j * 16 + fr][ks + kq];
        }
#pragma unroll
        for (int i = 0; i < 4; i++)
#pragma unroll
          for (int j = 0; j < 2; j++) {
            acc[i][j] = __builtin_amdgcn_mfma_f32_16x16x32_bf16(
                alo[i], bh[j], acc[i][j], 0, 0, 0);
            acc[i][j] = __builtin_amdgcn_mfma_f32_16x16x32_bf16(
                ah[i], blo[j], acc[i][j], 0, 0, 0);
            acc[i][j] = __builtin_amdgcn_mfma_f32_16x16x32_bf16(
                ah[i], bh[j], acc[i][j], 0, 0, 0);
          }
      }
      __syncthreads();
    }
#pragma unroll
    for (int i = 0; i < 4; i++)
#pragma unroll
      for (int j = 0; j < 2; j++)
#pragma unroll
        for (int r = 0; r < 4; r++) {
          size_t idx = (size_t)(bm + m0 + i * 16 + cr + r) * ZC +
                       (bn + n0 + j * 16 + cc);
          C[idx] = acc[i][j][r];
        }
  }
}

// ------------- k_redprep: reduce chunk c (+ prep chunk c+1) -----------------
__device__ __forceinline__ void load8p(const unsigned int* p, float* re,
                                       float* im) {
  uint4 u0 = ((const uint4*)p)[0], u1 = ((const uint4*)p)[1];
  re[0] = __uint_as_float(u0.x << 16); im[0] = __uint_as_float(u0.x & 0xffff0000u);
  re[1] = __uint_as_float(u0.y << 16); im[1] = __uint_as_float(u0.y & 0xffff0000u);
  re[2] = __uint_as_float(u0.z << 16); im[2] = __uint_as_float(u0.z & 0xffff0000u);
  re[3] = __uint_as_float(u0.w << 16); im[3] = __uint_as_float(u0.w & 0xffff0000u);
  re[4] = __uint_as_float(u1.x << 16); im[4] = __uint_as_float(u1.x & 0xffff0000u);
  re[5] = __uint_as_float(u1.y << 16); im[5] = __uint_as_float(u1.y & 0xffff0000u);
  re[6] = __uint_as_float(u1.z << 16); im[6] = __uint_as_float(u1.z & 0xffff0000u);
  re[7] = __uint_as_float(u1.w << 16); im[7] = __uint_as_float(u1.w & 0xffff0000u);
}
__device__ __forceinline__ void load8d(const float* p, float* o) {
  float4 f0 = ((const float4*)p)[0], f1 = ((const float4*)p)[1];
  o[0] = f0.x; o[1] = f0.y; o[2] = f0.z; o[3] = f0.w;
  o[4] = f1.x; o[5] = f1.y; o[6] = f1.z; o[7] = f1.w;
}

__global__ __launch_bounds__(256) void k_redprep(
    const unsigned int* __restrict__ Cpk, const float* __restrict__ den,
    float* __restrict__ out, const float* __restrict__ gMN,
    const float* __restrict__ Mm, const bf16* __restrict__ gxHi,
    const bf16* __restrict__ gxLo, const float* __restrict__ Xm,
    unsigned char* __restrict__ B8Next, int ZC, int zg0) {
  __shared__ float sm[64][65];
  const int bid = blockIdx.x, tid = threadIdx.x;
  if (bid >= 500) {
    int pid = bid - 500;
    int j0 = (pid & 31) * 64, zl0 = (pid >> 5) * 64;
    int zg0n = zg0 + ZC;
    build_mn(gMN, Mm, B8Next, j0, zl0, zg0n, ZC, tid, sm);
    build_x(gxHi, gxLo, Xm, B8Next, j0, zl0, zg0n, ZC, tid);
    return;
  }
  const size_t PS = (size_t)1024 * ZC;
  int a = bid * 2 + (tid >> 7);
  int zt = tid & 127;
  float acc = 0.f;
  for (int z = zt * 8; z < ZC; z += 1024) {
    if (zg0 + z >= 2000) break;
    size_t base = (size_t)a * ZC + z;
    float mdr[8], mdi[8], xdr[8], xdi[8], im[8], ix[8];
    load8d(den + 0 * PS + base, mdr);
    load8d(den + 1 * PS + base, mdi);
    load8d(den + 2 * PS + base, xdr);
    load8d(den + 3 * PS + base, xdi);
#pragma unroll
    for (int e = 0; e < 8; ++e) {
      im[e] = 1.f / (mdr[e] * mdr[e] + mdi[e] * mdi[e]);
      ix[e] = 1.f / (xdr[e] * xdr[e] + xdi[e] * xdi[e]);
    }
#pragma unroll
    for (int d = 0; d < 8; ++d) {
      float ar[8], ai[8], br[8], bi[8];
      load8p(Cpk + (size_t)d * PS + base, ar, ai);
      load8p(Cpk + (size_t)(8 + d) * PS + base, br, bi);
#pragma unroll
      for (int e = 0; e < 8; ++e) {
        float r1 = (ar[e] * mdr[e] + ai[e] * mdi[e]) * im[e];
        float i1 = (ai[e] * mdr[e] - ar[e] * mdi[e]) * im[e];
        float r2 = (br[e] * xdr[e] + bi[e] * xdi[e]) * ix[e];
        float i2 = (bi[e] * xdr[e] - br[e] * xdi[e]) * ix[e];
        float dr = r1 - r2, di = i1 - i2;
        acc += dr * dr + di * di;
      }
    }
  }
  for (int off = 32; off; off >>= 1) acc += __shfl_down(acc, off, 64);
  __shared__ float red[4];
  if (!(tid & 63)) red[tid >> 6] = acc;
  __syncthreads();
  if (!tid)
    atomicAdd(out, (red[0] + red[1] + red[2] + red[3]) * (1.f / 2000000.f));
}

// ============================================================================
extern "C" void kernel_launch(void* const* d_in, const int* in_sizes, int n_in,
                              void* d_out, int out_size, void* d_ws,
                              size_t ws_size, hipStream_t stream) {
  const float* Mm  = (const float*)d_in[0];
  const float* Nm  = (const float*)d_in[1];
  const float* Xm  = (const float*)d_in[2];
  const float* ll  = (const float*)d_in[3];
  const float* K11 = (const float*)d_in[4];
  const float* K12 = (const float*)d_in[5];
  const float* gMN = (const float*)d_in[6];
  const float* gN  = (const float*)d_in[7];
  const float* al  = (const float*)d_in[8];

  char* ws = (char*)d_ws;
  const size_t MB = 1024 * 1024;
  bf16* AphH = (bf16*)(ws);                       // 16 MB
  bf16* AphL = (bf16*)(ws + 16 * MB);             // 16 MB
  unsigned char* Aph8 = (unsigned char*)(ws + 32 * MB);  // 8 MB (fp8 phases)
  bf16* gxHi = (bf16*)(ws + 40 * MB);             // 8 MB
  bf16* gxLo = (bf16*)(ws + 48 * MB);             // 8 MB
  bf16* BtNh = (bf16*)(ws + 56 * MB);             // 8 MB
  bf16* BtNl = (bf16*)(ws + 64 * MB);             // 8 MB
  char* chunkRgn = ws + 72 * MB;

  // chunk: B8 16 fp8 planes (32768*ZC) | den (16384*ZC) | Cpk (65536*ZC)
  // transients (Kbf/K12T/K12TL, 24 MB) after the chunk region.
  size_t fixedNeed = 96 * MB;  // 72 fixed + 24 transients
  size_t avail = (ws_size > fixedNeed) ? ws_size - fixedNeed : 0;
  int ZC = 2048;
  while (ZC > 128 && (size_t)114688 * ZC > avail) ZC >>= 1;
  int NC = 2048 / ZC;
  unsigned char* B8c = (unsigned char*)(chunkRgn);
  float* denc = (float*)(chunkRgn + (size_t)32768 * ZC);
  unsigned int* Cpkc = (unsigned int*)(chunkRgn + (size_t)49152 * ZC);
  char* trans = chunkRgn + (size_t)114688 * ZC;
  bf16* Kbf   = (bf16*)(trans);
  bf16* K12T  = (bf16*)(trans + 8 * MB);
  bf16* K12TL = (bf16*)(trans + 16 * MB);

  int NBP = 32 * (ZC / 64);  // prep blocks per chunk

  k_cvt<<<dim3(4096), dim3(256), 0, stream>>>(K11, K12, gN, Kbf, K12T, K12TL,
                                              BtNh, BtNl, (float*)d_out);
  k_big<<<dim3(1280 + NBP), dim3(256), 0, stream>>>(
      K12T, K12TL, Kbf, ll, al, Nm, Xm, gMN, Mm, gxHi, gxLo, AphH, AphL, Aph8,
      B8c, ZC);
  k_prepX<<<dim3(NBP), dim3(256), 0, stream>>>(gxHi, gxLo, Xm, B8c, ZC);
  for (int c = 0; c < NC; ++c) {
    int zg0 = c * ZC;
    k_mm<<<dim3(8, ZC / 128, 24), dim3(256), 0, stream>>>(
        AphH, AphL, Aph8, B8c, BtNh, BtNl, gxHi, gxLo, Cpkc, denc, ZC, zg0);
    int nblk = (c + 1 < NC) ? 500 + NBP : 500;
    k_redprep<<<dim3(nblk), dim3(256), 0, stream>>>(
        Cpkc, denc, (float*)d_out, gMN, Mm, gxHi, gxLo, Xm, B8c, ZC, zg0);
  }
  (void)in_sizes; (void)n_in; (void)out_size;
}